// Round 10
// baseline (645.783 us; speedup 1.0000x reference)
//
#include <hip/hip_runtime.h>
#include <hip/hip_bf16.h>

// CliffordEPBottleneck: 10x { rho=tanh(h); drive=W_sym@rho+x; h=0.9h+0.1(1-rho^2)drive }
// Core: 10x GEMM (1024 x 4096 x 4096) bf16 MFMA.
//
// R10: split-K=4 (was 2). W/A cache traffic is independent of K-split
// (disjoint K-ranges), so traffic stays 512 MB while grid doubles to 1024 =
// 4 blk/CU = 16 waves/CU (R7's occupancy, R9's traffic). R7/R9 showed
// effective L2/L3 BW scales with waves/CU: 16.9 TB/s @16 vs 12.8 @8.
// Structure otherwise identical to R9: BM=BN=128, BK=32, frag-packed B via
// global_load_lds ring-4, A direct-to-reg from packed P, counted vmcnt(10),
// XCD-partitioned decode. Dp = 4 bf16 planes; combine sums 4.

#define NODES 4096
#define KDIM  4096
#define MDIM  1024
#define DLEN  16384
#define HALF_ELEMS 4194304   // MDIM*NODES (one partial plane)

typedef __attribute__((ext_vector_type(8))) __bf16 bf16x8;
typedef __attribute__((ext_vector_type(8))) unsigned short u16x8;
typedef __attribute__((ext_vector_type(4))) float  f32x4;

static __device__ __forceinline__ unsigned short f32_to_bf16(float f) {
    unsigned int u = __float_as_uint(f);
    u += 0x7fffu + ((u >> 16) & 1u);   // round-to-nearest-even
    return (unsigned short)(u >> 16);
}
static __device__ __forceinline__ float bf16_to_f32(unsigned short u) {
    return __uint_as_float(((unsigned int)u) << 16);
}

// ---------------------------------------------------------------------------
// Kernel 1: Wbp = bf16(0.5*(W+W^T)) packed in B-fragment order.
// Element (n, k) at ((k>>5)*256 + (n>>4))*512 + ((n&15)|(((k>>3)&3)<<4))*8 + (k&7)
// ---------------------------------------------------------------------------
__global__ __launch_bounds__(256)
void symw_kernel(const float* __restrict__ W, unsigned short* __restrict__ Wbp) {
    __shared__ float Ta[64][64];
    __shared__ float Tb[64][65];
    const int tn = blockIdx.y, tm = blockIdx.x;
    const int c  = threadIdx.x & 63;
    const int r0 = threadIdx.x >> 6;
#pragma unroll
    for (int rr = 0; rr < 16; ++rr) {
        int r = r0 * 16 + rr;
        Ta[r][c] = W[(size_t)(tn * 64 + r) * 4096 + tm * 64 + c];
        Tb[r][c] = W[(size_t)(tm * 64 + r) * 4096 + tn * 64 + c];
    }
    __syncthreads();
#pragma unroll
    for (int rr = 0; rr < 16; ++rr) {
        int r = r0 * 16 + rr;
        float v = 0.5f * (Ta[r][c] + Tb[c][r]);
        int n = tn * 64 + r;
        int k = tm * 64 + c;
        size_t addr = ((size_t)(k >> 5) * 256 + (n >> 4)) * 512
                    + (size_t)((n & 15) | (((k >> 3) & 3) << 4)) * 8 + (k & 7);
        Wbp[addr] = f32_to_bf16(v);
    }
}

// ---------------------------------------------------------------------------
// Kernel 2: h = x ; P0 = packed bf16(tanh(x)) in A-fragment order.
// ---------------------------------------------------------------------------
__global__ __launch_bounds__(256)
void init_kernel(const float* __restrict__ x, float* __restrict__ h,
                 unsigned short* __restrict__ P0) {
    int idx = blockIdx.x * blockDim.x + threadIdx.x;   // over B*NODES = 1M
    int b = idx >> 12;
    int m = idx & 4095;
    f32x4 xv = *(const f32x4*)(x + (size_t)idx * 4);
    *(f32x4*)(h + (size_t)idx * 4) = xv;
    size_t base = ((size_t)(m >> 5) * 64 + (b >> 2)) * 512
                + (size_t)((m >> 3) & 3) * 128 + (m & 7);
#pragma unroll
    for (int c = 0; c < 4; ++c) {
        P0[base + (size_t)((b & 3) * 4 + c) * 8] = f32_to_bf16(tanhf(xv[c]));
    }
}

// ---------------------------------------------------------------------------
// Kernel 3: split-K=4 GEMM. grid 1024 (flat, XCD-partitioned decode), 256 thr
// (4 waves 2x2). BM=BN=128 BK=32; wave = 64x64 (mi4 x ni4). 32 k-tiles/block.
// ---------------------------------------------------------------------------
__global__ __launch_bounds__(256, 4)
void gemm_kernel(const unsigned short* __restrict__ Pcur,
                 const unsigned short* __restrict__ Wbp,
                 unsigned short* __restrict__ Dp) {
    __shared__ unsigned short Bs[4 * 4096];   // ring-4 x 8 KB (128n x 32k frag-major)

    // XCD-partitioned decode: xcd = id&7 owns bx in {4*xcd .. 4*xcd+3}
    const int id   = blockIdx.x;                       // 0..1023
    const int bx   = (id & 7) * 4 + ((id >> 3) & 3);   // 0..31
    const int by   = (id >> 5) & 7;                    // 0..7
    const int ks   = id >> 8;                          // 0..3
    const int T0   = ks * 32;                          // first local k32-tile

    const int tid  = threadIdx.x;
    const int w    = tid >> 6;
    const int lane = tid & 63;
    const int wm   = w >> 1;                 // 0..1
    const int wn   = w & 1;                  // 0..1

    // staging: 2 chunks/thread (B tile = 8 KB = 512 x 16B)
    size_t soff[2]; int dsto[2];
#pragma unroll
    for (int j = 0; j < 2; ++j) {
        int c = tid + 256 * j;               // 0..511
        soff[j] = ((size_t)(bx * 8 + (c >> 6))) * 512 + (size_t)(c & 63) * 8;
        dsto[j] = c * 8;
    }
    // A frags: rows (by*8 + wm*4 + mi) in 16-row units
    size_t aoff[4];
#pragma unroll
    for (int mi = 0; mi < 4; ++mi)
        aoff[mi] = ((size_t)(by * 8 + wm * 4 + mi)) * 512 + (size_t)lane * 8;
    const int boff = (wn * 4) * 512 + lane * 8;   // + ni*512 (+slot*4096)

    f32x4 acc[4][4];
#pragma unroll
    for (int mi = 0; mi < 4; ++mi)
#pragma unroll
        for (int ni = 0; ni < 4; ++ni)
            acc[mi][ni] = (f32x4){0.f, 0.f, 0.f, 0.f};

    bf16x8 aA[4], aB[4];

#define TC(t) ((t) < 31 ? (t) : 31)   // clamp local tile index (uniform tail)

#define STAGE(slot, tl)                                                         \
    do {                                                                        \
        const unsigned short* src = Wbp + (size_t)(T0 + (tl)) * 131072;         \
        _Pragma("unroll")                                                       \
        for (int j = 0; j < 2; ++j) {                                           \
            __builtin_amdgcn_global_load_lds(                                   \
                (const __attribute__((address_space(1))) void*)(src + soff[j]), \
                (__attribute__((address_space(3))) void*)                      \
                    (Bs + (slot) * 4096 + dsto[j]),                             \
                16, 0, 0);                                                      \
        }                                                                       \
    } while (0)

#define LOADA(s, tl)                                                            \
    do {                                                                        \
        const unsigned short* Pt = Pcur + (size_t)(T0 + (tl)) * 32768;          \
        _Pragma("unroll")                                                       \
        for (int mi = 0; mi < 4; ++mi)                                          \
            s[mi] = *(const bf16x8*)(Pt + aoff[mi]);                            \
    } while (0)

#define COMPUTE(slot, s)                                                        \
    do {                                                                        \
        const unsigned short* Bb = Bs + (slot) * 4096;                          \
        bf16x8 bfr[4];                                                          \
        _Pragma("unroll")                                                       \
        for (int ni = 0; ni < 4; ++ni)                                          \
            bfr[ni] = *(const bf16x8*)(Bb + boff + ni * 512);                   \
        _Pragma("unroll")                                                       \
        for (int mi = 0; mi < 4; ++mi)                                          \
            _Pragma("unroll")                                                   \
            for (int ni = 0; ni < 4; ++ni)                                      \
                acc[mi][ni] = __builtin_amdgcn_mfma_f32_16x16x32_bf16(          \
                    s[mi], bfr[ni], acc[mi][ni], 0, 0, 0);                      \
    } while (0)

    // prologue: stages 0..2, A0 (issue order fixes vmcnt accounting)
    STAGE(0, 0);        // 2
    LOADA(aA, 0);       // 4
    STAGE(1, 1);        // 2
    STAGE(2, 2);        // 2
    // iter 0:
    LOADA(aB, 1);       // 4
    STAGE(3, 3);        // 2   -> 16 outstanding
    asm volatile("s_waitcnt vmcnt(10)" ::: "memory");  // S0 + A0 landed
    __builtin_amdgcn_s_barrier();
    COMPUTE(0, aA);

    // t = 1..30 in pairs; steady vmcnt(10)
    for (int tp = 0; tp < 15; ++tp) {
        const int t = 1 + 2 * tp;            // odd tile -> aB
        LOADA(aA, TC(t + 1));
        STAGE((t + 3) & 3, TC(t + 3));
        asm volatile("s_waitcnt vmcnt(10)" ::: "memory");
        __builtin_amdgcn_s_barrier();
        COMPUTE(t & 3, aB);

        const int u = t + 1;                 // even tile -> aA
        LOADA(aB, TC(u + 1));
        STAGE((u + 3) & 3, TC(u + 3));
        asm volatile("s_waitcnt vmcnt(10)" ::: "memory");
        __builtin_amdgcn_s_barrier();
        COMPUTE(u & 3, aA);
    }
    // t = 31 (odd -> aB)
    asm volatile("s_waitcnt vmcnt(0)" ::: "memory");
    __builtin_amdgcn_s_barrier();
    COMPUTE(31 & 3, aB);
#undef STAGE
#undef LOADA
#undef COMPUTE
#undef TC

    // partial write, bf16. C/D: col=lane&15, row=(lane>>4)*4+reg.
    const int lr = lane & 15, lk = lane >> 4;
    unsigned short* D = Dp + (size_t)ks * HALF_ELEMS;
#pragma unroll
    for (int mi = 0; mi < 4; ++mi) {
        int i0 = by * 128 + wm * 64 + mi * 16 + lk * 4;
#pragma unroll
        for (int ni = 0; ni < 4; ++ni) {
            int n = bx * 128 + wn * 64 + ni * 16 + lr;
#pragma unroll
            for (int r = 0; r < 4; ++r)
                D[(size_t)(i0 + r) * NODES + n] = f32_to_bf16(acc[mi][ni][r]);
        }
    }
}

// ---------------------------------------------------------------------------
// Kernel 4: combine 4 partials + epilogue. Last step: write out only.
// ---------------------------------------------------------------------------
__global__ __launch_bounds__(256)
void combine_kernel(const unsigned short* __restrict__ Dp,
                    const float* __restrict__ x,
                    float* __restrict__ h,
                    unsigned short* __restrict__ Pnxt,
                    float* __restrict__ out) {
    int g  = blockIdx.x * 256 + threadIdx.x;   // 0..131071
    int b  = g >> 9;
    int mg = (g & 511) << 3;                   // m base (multiple of 8)
    size_t hbase = (size_t)b * DLEN + (size_t)mg * 4;

    f32x4 hv[8], xv[8];
#pragma unroll
    for (int e = 0; e < 8; ++e) {
        hv[e] = *(const f32x4*)(h + hbase + e * 4);
        xv[e] = *(const f32x4*)(x + hbase + e * 4);
    }
    u16x8 d0[4], d1[4], d2[4], d3[4];
#pragma unroll
    for (int c = 0; c < 4; ++c) {
        size_t off = (size_t)(b * 4 + c) * NODES + mg;
        d0[c] = *(const u16x8*)(Dp + off);
        d1[c] = *(const u16x8*)(Dp + HALF_ELEMS + off);
        d2[c] = *(const u16x8*)(Dp + 2 * (size_t)HALF_ELEMS + off);
        d3[c] = *(const u16x8*)(Dp + 3 * (size_t)HALF_ELEMS + off);
    }
    u16x8 pn[4];
    float o[8];
#pragma unroll
    for (int e = 0; e < 8; ++e) {
#pragma unroll
        for (int c = 0; c < 4; ++c) {
            float p = (bf16_to_f32(d0[c][e]) + bf16_to_f32(d1[c][e]))
                    + (bf16_to_f32(d2[c][e]) + bf16_to_f32(d3[c][e]));
            float hvv  = hv[e][c];
            float rho  = tanhf(hvv);
            float drive = p + xv[e][c];
            float hnew = 0.9f * hvv + 0.1f * (1.0f - rho * rho) * drive;
            hv[e][c] = hnew;
            pn[c][e] = f32_to_bf16(tanhf(hnew));
            if (c == 0) o[e] = hnew;
        }
    }
    if (Pnxt) {   // not the last step: update h and packed rho
#pragma unroll
        for (int e = 0; e < 8; ++e)
            *(f32x4*)(h + hbase + e * 4) = hv[e];
#pragma unroll
        for (int c = 0; c < 4; ++c) {
            size_t pa = (size_t)(mg >> 5) * 32768 + (size_t)(b >> 2) * 512
                      + (size_t)(((b & 3) * 4 + c) | (((mg >> 3) & 3) << 4)) * 8;
            *(u16x8*)(Pnxt + pa) = pn[c];
        }
    }
    if (out) {
        *(f32x4*)(out + (size_t)b * NODES + mg)     = (f32x4){o[0], o[1], o[2], o[3]};
        *(f32x4*)(out + (size_t)b * NODES + mg + 4) = (f32x4){o[4], o[5], o[6], o[7]};
    }
}

// ---------------------------------------------------------------------------
extern "C" void kernel_launch(void* const* d_in, const int* in_sizes, int n_in,
                              void* d_out, int out_size, void* d_ws, size_t ws_size,
                              hipStream_t stream) {
    const float* x = (const float*)d_in[0];   // (256, 16384) f32
    const float* W = (const float*)d_in[1];   // (4096, 4096) f32
    float* out = (float*)d_out;               // (256, 4096) f32

    char* ws = (char*)d_ws;
    // ws: Wbp 32MB | P0 8MB | P1 8MB | h 16MB | Dp 32MB  (= 96 MB)
    unsigned short* Wbp = (unsigned short*)(ws);
    unsigned short* P0  = (unsigned short*)(ws + ((size_t)32 << 20));
    unsigned short* P1  = (unsigned short*)(ws + ((size_t)40 << 20));
    float*          h   = (float*)(ws + ((size_t)48 << 20));
    unsigned short* Dp  = (unsigned short*)(ws + ((size_t)64 << 20));

    symw_kernel<<<dim3(64, 64), 256, 0, stream>>>(W, Wbp);
    init_kernel<<<dim3(4096), 256, 0, stream>>>(x, h, P0);

    unsigned short* pc = P0;
    unsigned short* pn = P1;
    for (int s = 0; s < 10; ++s) {
        gemm_kernel<<<dim3(1024), 256, 0, stream>>>(pc, Wbp, Dp);
        combine_kernel<<<dim3(512), 256, 0, stream>>>(
            Dp, x, h, (s == 9) ? nullptr : pn, (s == 9) ? out : nullptr);
        unsigned short* t = pc; pc = pn; pn = t;
    }
}

// Round 12
// 618.399 us; speedup vs baseline: 1.0443x; 1.0443x over previous
//
#include <hip/hip_runtime.h>
#include <hip/hip_bf16.h>

// CliffordEPBottleneck: 10x { rho=tanh(h); drive=W_sym@rho+x; h=0.9h+0.1(1-rho^2)drive }
// Core: 10x GEMM (1024 x 4096 x 4096) bf16 MFMA.
//
// R12 = R11 with the race fixed. R11 put phase ds_reads BEFORE the step
// barrier: own-wave vmcnt(10) doesn't cover OTHER waves' global_load_lds ->
// read-before-landed -> NaN (the guide's m152 failure mode). Correct order,
// per K-step: vmcnt(10) -> s_barrier -> STAGE(t+2) -> LOADA(t+1) ->
// {ds_read quad -> setprio(1) 16 MFMA setprio(0)} x2. One barrier/step.
// Geometry kept from R11: BM=256 BN=128 BK=64 splitK=2, grid 256 = 1 blk/CU,
// 512 thr = 8 waves (4M x 2N), wave tile 64x64. Traffic 384 MB/step (-25%
// vs R9), 32 MFMA / 8 ds_read per wave-step (2x R9 density).

#define NODES 4096
#define KDIM  4096
#define MDIM  1024
#define DLEN  16384
#define HALF_ELEMS 4194304   // MDIM*NODES (one partial plane)

typedef __attribute__((ext_vector_type(8))) __bf16 bf16x8;
typedef __attribute__((ext_vector_type(8))) unsigned short u16x8;
typedef __attribute__((ext_vector_type(4))) float  f32x4;

static __device__ __forceinline__ unsigned short f32_to_bf16(float f) {
    unsigned int u = __float_as_uint(f);
    u += 0x7fffu + ((u >> 16) & 1u);   // round-to-nearest-even
    return (unsigned short)(u >> 16);
}
static __device__ __forceinline__ float bf16_to_f32(unsigned short u) {
    return __uint_as_float(((unsigned int)u) << 16);
}

// ---------------------------------------------------------------------------
// Kernel 1: Wbp = bf16(0.5*(W+W^T)) packed in B-fragment order.
// Element (n, k) at ((k>>5)*256 + (n>>4))*512 + ((n&15)|(((k>>3)&3)<<4))*8 + (k&7)
// ---------------------------------------------------------------------------
__global__ __launch_bounds__(256)
void symw_kernel(const float* __restrict__ W, unsigned short* __restrict__ Wbp) {
    __shared__ float Ta[64][64];
    __shared__ float Tb[64][65];
    const int tn = blockIdx.y, tm = blockIdx.x;
    const int c  = threadIdx.x & 63;
    const int r0 = threadIdx.x >> 6;
#pragma unroll
    for (int rr = 0; rr < 16; ++rr) {
        int r = r0 * 16 + rr;
        Ta[r][c] = W[(size_t)(tn * 64 + r) * 4096 + tm * 64 + c];
        Tb[r][c] = W[(size_t)(tm * 64 + r) * 4096 + tn * 64 + c];
    }
    __syncthreads();
#pragma unroll
    for (int rr = 0; rr < 16; ++rr) {
        int r = r0 * 16 + rr;
        float v = 0.5f * (Ta[r][c] + Tb[c][r]);
        int n = tn * 64 + r;
        int k = tm * 64 + c;
        size_t addr = ((size_t)(k >> 5) * 256 + (n >> 4)) * 512
                    + (size_t)((n & 15) | (((k >> 3) & 3) << 4)) * 8 + (k & 7);
        Wbp[addr] = f32_to_bf16(v);
    }
}

// ---------------------------------------------------------------------------
// Kernel 2: h = x ; P0 = packed bf16(tanh(x)) in A-fragment order.
// ---------------------------------------------------------------------------
__global__ __launch_bounds__(256)
void init_kernel(const float* __restrict__ x, float* __restrict__ h,
                 unsigned short* __restrict__ P0) {
    int idx = blockIdx.x * blockDim.x + threadIdx.x;   // over B*NODES = 1M
    int b = idx >> 12;
    int m = idx & 4095;
    f32x4 xv = *(const f32x4*)(x + (size_t)idx * 4);
    *(f32x4*)(h + (size_t)idx * 4) = xv;
    size_t base = ((size_t)(m >> 5) * 64 + (b >> 2)) * 512
                + (size_t)((m >> 3) & 3) * 128 + (m & 7);
#pragma unroll
    for (int c = 0; c < 4; ++c) {
        P0[base + (size_t)((b & 3) * 4 + c) * 8] = f32_to_bf16(tanhf(xv[c]));
    }
}

// ---------------------------------------------------------------------------
// Kernel 3: 8-wave split-K=2 GEMM. grid 256 (flat, XCD-grouped decode),
// 512 thr = 8 waves (4M x 2N). BM=256 BN=128 BK=64 (2 k32 frags/step).
// 32 K-steps. B ring-3 LDS (frag-major, conflict-free). A direct-to-reg.
// ---------------------------------------------------------------------------
__global__ __launch_bounds__(512, 1)
void gemm_kernel(const unsigned short* __restrict__ Pcur,
                 const unsigned short* __restrict__ Wbp,
                 unsigned short* __restrict__ Dp) {
    __shared__ unsigned short Bs[3 * 8192];   // 3 ring slots x 16 KB

    // XCD-grouped decode: the 4 by-blocks sharing one (bx,ks) W-slice land
    // on the same XCD (per-XCD W working set = 4 MB = L2).
    const int id = blockIdx.x;                          // 0..255
    const int bx = (id & 7) | (((id >> 5) & 3) << 3);   // 0..31
    const int by = (id >> 3) & 3;                       // 0..3
    const int ks = id >> 7;                             // 0..1

    const int tid  = threadIdx.x;            // 0..511
    const int w    = tid >> 6;
    const int lane = tid & 63;
    const int wm   = w >> 1;                 // 0..3 (M)
    const int wn   = w & 1;                  // 0..1 (N)

    // B staging: 2 chunks/thread; chunk c (0..1023) -> LDS frag f=c>>6 (kf*8+nf)
    size_t soff[2];
#pragma unroll
    for (int j = 0; j < 2; ++j) {
        int c  = tid + 512 * j;
        int f  = c >> 6;                     // 0..15
        int kf = f >> 3, nf = f & 7;
        soff[j] = ((size_t)kf * 256 + bx * 8 + nf) * 512 + (size_t)(c & 63) * 8;
    }
    // A frags: mr = by*16 + wm*4 + mi
    size_t aoff[4];
#pragma unroll
    for (int mi = 0; mi < 4; ++mi)
        aoff[mi] = ((size_t)(by * 16 + wm * 4 + mi)) * 512 + (size_t)lane * 8;

    f32x4 acc[4][4];
#pragma unroll
    for (int mi = 0; mi < 4; ++mi)
#pragma unroll
        for (int ni = 0; ni < 4; ++ni)
            acc[mi][ni] = (f32x4){0.f, 0.f, 0.f, 0.f};

    bf16x8 aE[4][2], aO[4][2];

    // global k32 base for local K-step t: k32 = ks*64 + 2t (+kk)
#define STAGE(slot, t)                                                          \
    do {                                                                        \
        const unsigned short* src = Wbp + (size_t)(ks * 64 + 2 * (t)) * 131072; \
        _Pragma("unroll")                                                       \
        for (int j = 0; j < 2; ++j) {                                           \
            int c = tid + 512 * j;                                              \
            __builtin_amdgcn_global_load_lds(                                   \
                (const __attribute__((address_space(1))) void*)(src + soff[j]), \
                (__attribute__((address_space(3))) void*)                      \
                    (Bs + (slot) * 8192 + c * 8),                               \
                16, 0, 0);                                                      \
        }                                                                       \
    } while (0)

#define LOADA(s, t)                                                             \
    do {                                                                        \
        const unsigned short* Pt = Pcur + (size_t)(ks * 64 + 2 * (t)) * 32768;  \
        _Pragma("unroll")                                                       \
        for (int mi = 0; mi < 4; ++mi)                                          \
            _Pragma("unroll")                                                   \
            for (int kk = 0; kk < 2; ++kk)                                      \
                s[mi][kk] = *(const bf16x8*)(Pt + (size_t)kk * 32768 + aoff[mi]); \
    } while (0)

    // one phase: ds_read one ni-pair quadrant (AFTER the step barrier), then
    // prio-wrapped MFMA cluster. Intra-wave lgkmcnt (compiler) orders read->use;
    // slot isn't overwritten until after the NEXT step's barrier.
#define PHASE(slot, p, s)                                                       \
    do {                                                                        \
        bf16x8 bq[2][2];                                                        \
        _Pragma("unroll")                                                       \
        for (int i = 0; i < 2; ++i)                                             \
            _Pragma("unroll")                                                   \
            for (int kk = 0; kk < 2; ++kk)                                      \
                bq[i][kk] = *(const bf16x8*)(Bs + (slot) * 8192                 \
                    + (kk * 8 + wn * 4 + (p) * 2 + i) * 512 + lane * 8);        \
        __builtin_amdgcn_s_setprio(1);                                          \
        _Pragma("unroll")                                                       \
        for (int mi = 0; mi < 4; ++mi)                                          \
            _Pragma("unroll")                                                   \
            for (int i = 0; i < 2; ++i)                                         \
                _Pragma("unroll")                                               \
                for (int kk = 0; kk < 2; ++kk)                                  \
                    acc[mi][(p) * 2 + i] = __builtin_amdgcn_mfma_f32_16x16x32_bf16( \
                        s[mi][kk], bq[i][kk], acc[mi][(p) * 2 + i], 0, 0, 0);   \
        __builtin_amdgcn_s_setprio(0);                                          \
    } while (0)

    // prologue: S(0), S(1), A(0)  -> 12 VMEM ops/thread outstanding
    STAGE(0, 0);
    STAGE(1, 1);
    LOADA(aE, 0);

    // steady: per step issues S:2 + A:8 = 10 -> vmcnt(10) == own S(t) landed;
    // barrier -> ALL waves' S(t) landed AND step t-1 readers done.
    for (int tp = 0; tp < 15; ++tp) {
        const int t = 2 * tp;
        // even tile t: compute aE
        asm volatile("s_waitcnt vmcnt(10)" ::: "memory");
        asm volatile("s_barrier" ::: "memory");
        STAGE((t + 2) % 3, t + 2);
        LOADA(aO, t + 1);
        PHASE(t % 3, 0, aE);
        PHASE(t % 3, 1, aE);
        // odd tile t+1: compute aO
        asm volatile("s_waitcnt vmcnt(10)" ::: "memory");
        asm volatile("s_barrier" ::: "memory");
        STAGE((t + 3) % 3, t + 3);
        LOADA(aE, t + 2);
        PHASE((t + 1) % 3, 0, aO);
        PHASE((t + 1) % 3, 1, aO);
    }
    // t = 30 (slot 0): nothing left to stage
    asm volatile("s_waitcnt vmcnt(10)" ::: "memory");
    asm volatile("s_barrier" ::: "memory");
    LOADA(aO, 31);
    PHASE(0, 0, aE);
    PHASE(0, 1, aE);
    // t = 31 (slot 1): S(31) is oldest remaining pair
    asm volatile("s_waitcnt vmcnt(8)" ::: "memory");
    asm volatile("s_barrier" ::: "memory");
    PHASE(1, 0, aO);
    PHASE(1, 1, aO);
#undef STAGE
#undef LOADA
#undef PHASE

    // partial write, bf16. C/D: col=lane&15, row=(lane>>4)*4+reg.
    const int lr = lane & 15, lk = lane >> 4;
    unsigned short* D = Dp + (size_t)ks * HALF_ELEMS;
#pragma unroll
    for (int mi = 0; mi < 4; ++mi) {
        int i0 = by * 256 + wm * 64 + mi * 16 + lk * 4;
#pragma unroll
        for (int ni = 0; ni < 4; ++ni) {
            int n = bx * 128 + wn * 64 + ni * 16 + lr;
#pragma unroll
            for (int r = 0; r < 4; ++r)
                D[(size_t)(i0 + r) * NODES + n] = f32_to_bf16(acc[mi][ni][r]);
        }
    }
}

// ---------------------------------------------------------------------------
// Kernel 4: combine 2 partials + epilogue. Last step: write out only.
// ---------------------------------------------------------------------------
__global__ __launch_bounds__(256)
void combine_kernel(const unsigned short* __restrict__ Dp,
                    const float* __restrict__ x,
                    float* __restrict__ h,
                    unsigned short* __restrict__ Pnxt,
                    float* __restrict__ out) {
    int g  = blockIdx.x * 256 + threadIdx.x;   // 0..131071
    int b  = g >> 9;
    int mg = (g & 511) << 3;                   // m base (multiple of 8)
    size_t hbase = (size_t)b * DLEN + (size_t)mg * 4;

    f32x4 hv[8], xv[8];
#pragma unroll
    for (int e = 0; e < 8; ++e) {
        hv[e] = *(const f32x4*)(h + hbase + e * 4);
        xv[e] = *(const f32x4*)(x + hbase + e * 4);
    }
    u16x8 d0[4], d1[4];
#pragma unroll
    for (int c = 0; c < 4; ++c) {
        size_t off = (size_t)(b * 4 + c) * NODES + mg;
        d0[c] = *(const u16x8*)(Dp + off);
        d1[c] = *(const u16x8*)(Dp + HALF_ELEMS + off);
    }
    u16x8 pn[4];
    float o[8];
#pragma unroll
    for (int e = 0; e < 8; ++e) {
#pragma unroll
        for (int c = 0; c < 4; ++c) {
            float p    = bf16_to_f32(d0[c][e]) + bf16_to_f32(d1[c][e]);
            float hvv  = hv[e][c];
            float rho  = tanhf(hvv);
            float drive = p + xv[e][c];
            float hnew = 0.9f * hvv + 0.1f * (1.0f - rho * rho) * drive;
            hv[e][c] = hnew;
            pn[c][e] = f32_to_bf16(tanhf(hnew));
            if (c == 0) o[e] = hnew;
        }
    }
    if (Pnxt) {   // not the last step: update h and packed rho
#pragma unroll
        for (int e = 0; e < 8; ++e)
            *(f32x4*)(h + hbase + e * 4) = hv[e];
#pragma unroll
        for (int c = 0; c < 4; ++c) {
            size_t pa = (size_t)(mg >> 5) * 32768 + (size_t)(b >> 2) * 512
                      + (size_t)(((b & 3) * 4 + c) | (((mg >> 3) & 3) << 4)) * 8;
            *(u16x8*)(Pnxt + pa) = pn[c];
        }
    }
    if (out) {
        *(f32x4*)(out + (size_t)b * NODES + mg)     = (f32x4){o[0], o[1], o[2], o[3]};
        *(f32x4*)(out + (size_t)b * NODES + mg + 4) = (f32x4){o[4], o[5], o[6], o[7]};
    }
}

// ---------------------------------------------------------------------------
extern "C" void kernel_launch(void* const* d_in, const int* in_sizes, int n_in,
                              void* d_out, int out_size, void* d_ws, size_t ws_size,
                              hipStream_t stream) {
    const float* x = (const float*)d_in[0];   // (256, 16384) f32
    const float* W = (const float*)d_in[1];   // (4096, 4096) f32
    float* out = (float*)d_out;               // (256, 4096) f32

    char* ws = (char*)d_ws;
    // ws: Wbp 32MB | P0 8MB | P1 8MB | h 16MB | Dp 16MB  (= 80 MB)
    unsigned short* Wbp = (unsigned short*)(ws);
    unsigned short* P0  = (unsigned short*)(ws + ((size_t)32 << 20));
    unsigned short* P1  = (unsigned short*)(ws + ((size_t)40 << 20));
    float*          h   = (float*)(ws + ((size_t)48 << 20));
    unsigned short* Dp  = (unsigned short*)(ws + ((size_t)64 << 20));

    symw_kernel<<<dim3(64, 64), 256, 0, stream>>>(W, Wbp);
    init_kernel<<<dim3(4096), 256, 0, stream>>>(x, h, P0);

    unsigned short* pc = P0;
    unsigned short* pn = P1;
    for (int s = 0; s < 10; ++s) {
        gemm_kernel<<<dim3(256), 512, 0, stream>>>(pc, Wbp, Dp);
        combine_kernel<<<dim3(512), 256, 0, stream>>>(
            Dp, x, h, (s == 9) ? nullptr : pn, (s == 9) ? out : nullptr);
        unsigned short* t = pc; pc = pn; pn = t;
    }
}

// Round 13
// 550.538 us; speedup vs baseline: 1.1730x; 1.1233x over previous
//
#include <hip/hip_runtime.h>
#include <hip/hip_bf16.h>

// CliffordEPBottleneck: 10x { rho=tanh(h); drive=W_sym@rho+x; h=0.9h+0.1(1-rho^2)drive }
// Core: 10x GEMM (1024 x 4096 x 4096) bf16 MFMA.
//
// R13: gemm = R9 verbatim (40.0 us = ~860 TF, 95% of the documented ~900 TF
// plain-HIP single-phase ceiling; R10/R12 schedule variants all regressed).
// New: combine state in bf16 — h and x stored as bf16 (hb, xb), f32 compute
// in-register. Combine traffic 72 -> 48 MB/step (-33%). Quantization adds
// ~2e-3/step into a recurrence whose bf16-rho/W noise measured 0.0078 absmax;
// predicted absmax ~0.015 vs threshold 0.036.

#define NODES 4096
#define KDIM  4096
#define MDIM  1024
#define DLEN  16384
#define HALF_ELEMS 4194304   // MDIM*NODES (one partial plane)

typedef __attribute__((ext_vector_type(8))) __bf16 bf16x8;
typedef __attribute__((ext_vector_type(8))) unsigned short u16x8;
typedef __attribute__((ext_vector_type(4))) unsigned short u16x4;
typedef __attribute__((ext_vector_type(4))) float  f32x4;

static __device__ __forceinline__ unsigned short f32_to_bf16(float f) {
    unsigned int u = __float_as_uint(f);
    u += 0x7fffu + ((u >> 16) & 1u);   // round-to-nearest-even
    return (unsigned short)(u >> 16);
}
static __device__ __forceinline__ float bf16_to_f32(unsigned short u) {
    return __uint_as_float(((unsigned int)u) << 16);
}

// ---------------------------------------------------------------------------
// Kernel 1: Wbp = bf16(0.5*(W+W^T)) packed in B-fragment order.
// Element (n, k) at ((k>>5)*256 + (n>>4))*512 + ((n&15)|(((k>>3)&3)<<4))*8 + (k&7)
// ---------------------------------------------------------------------------
__global__ __launch_bounds__(256)
void symw_kernel(const float* __restrict__ W, unsigned short* __restrict__ Wbp) {
    __shared__ float Ta[64][64];
    __shared__ float Tb[64][65];
    const int tn = blockIdx.y, tm = blockIdx.x;
    const int c  = threadIdx.x & 63;
    const int r0 = threadIdx.x >> 6;
#pragma unroll
    for (int rr = 0; rr < 16; ++rr) {
        int r = r0 * 16 + rr;
        Ta[r][c] = W[(size_t)(tn * 64 + r) * 4096 + tm * 64 + c];
        Tb[r][c] = W[(size_t)(tm * 64 + r) * 4096 + tn * 64 + c];
    }
    __syncthreads();
#pragma unroll
    for (int rr = 0; rr < 16; ++rr) {
        int r = r0 * 16 + rr;
        float v = 0.5f * (Ta[r][c] + Tb[c][r]);
        int n = tn * 64 + r;
        int k = tm * 64 + c;
        size_t addr = ((size_t)(k >> 5) * 256 + (n >> 4)) * 512
                    + (size_t)((n & 15) | (((k >> 3) & 3) << 4)) * 8 + (k & 7);
        Wbp[addr] = f32_to_bf16(v);
    }
}

// ---------------------------------------------------------------------------
// Kernel 2: hb = bf16(x); xb = bf16(x); P0 = packed bf16(tanh(x)).
// ---------------------------------------------------------------------------
__global__ __launch_bounds__(256)
void init_kernel(const float* __restrict__ x,
                 unsigned short* __restrict__ hb,
                 unsigned short* __restrict__ xb,
                 unsigned short* __restrict__ P0) {
    int idx = blockIdx.x * blockDim.x + threadIdx.x;   // over B*NODES = 1M
    int b = idx >> 12;
    int m = idx & 4095;
    f32x4 xv = *(const f32x4*)(x + (size_t)idx * 4);
    u16x4 xq;
#pragma unroll
    for (int c = 0; c < 4; ++c) xq[c] = f32_to_bf16(xv[c]);
    *(u16x4*)(xb + (size_t)idx * 4) = xq;
    *(u16x4*)(hb + (size_t)idx * 4) = xq;
    size_t base = ((size_t)(m >> 5) * 64 + (b >> 2)) * 512
                + (size_t)((m >> 3) & 3) * 128 + (m & 7);
#pragma unroll
    for (int c = 0; c < 4; ++c) {
        P0[base + (size_t)((b & 3) * 4 + c) * 8] = f32_to_bf16(tanhf(xv[c]));
    }
}

// ---------------------------------------------------------------------------
// Kernel 3: split-K=2 GEMM (R9 verbatim). grid 512 (flat, XCD-partitioned),
// 256 thr (4 waves 2x2). BM=BN=128 BK=32; wave = 64x64 (mi4 x ni4).
// B frag-packed ring-4 LDS via global_load_lds, A direct-to-reg from packed P,
// counted vmcnt(10), 1 barrier/tile.
// ---------------------------------------------------------------------------
__global__ __launch_bounds__(256, 2)
void gemm_kernel(const unsigned short* __restrict__ Pcur,
                 const unsigned short* __restrict__ Wbp,
                 unsigned short* __restrict__ Dp) {
    __shared__ unsigned short Bs[4 * 4096];   // ring-4 x 8 KB (128n x 32k frag-major)

    // XCD-partitioned decode: xcd = id&7 owns bx in {4*xcd .. 4*xcd+3}
    const int id   = blockIdx.x;                       // 0..511
    const int bx   = (id & 7) * 4 + ((id >> 3) & 3);   // 0..31
    const int by   = (id >> 5) & 7;                    // 0..7
    const int ks   = id >> 8;                          // 0..1
    const int T0   = ks * 64;

    const int tid  = threadIdx.x;
    const int w    = tid >> 6;
    const int lane = tid & 63;
    const int wm   = w >> 1;                 // 0..1
    const int wn   = w & 1;                  // 0..1

    // staging: 2 chunks/thread (B tile = 8 KB = 512 x 16B)
    size_t soff[2]; int dsto[2];
#pragma unroll
    for (int j = 0; j < 2; ++j) {
        int c = tid + 256 * j;               // 0..511
        soff[j] = ((size_t)(bx * 8 + (c >> 6))) * 512 + (size_t)(c & 63) * 8;
        dsto[j] = c * 8;
    }
    // A frags: rows (by*8 + wm*4 + mi) in 16-row units
    size_t aoff[4];
#pragma unroll
    for (int mi = 0; mi < 4; ++mi)
        aoff[mi] = ((size_t)(by * 8 + wm * 4 + mi)) * 512 + (size_t)lane * 8;
    const int boff = (wn * 4) * 512 + lane * 8;   // + ni*512 (+slot*4096)

    f32x4 acc[4][4];
#pragma unroll
    for (int mi = 0; mi < 4; ++mi)
#pragma unroll
        for (int ni = 0; ni < 4; ++ni)
            acc[mi][ni] = (f32x4){0.f, 0.f, 0.f, 0.f};

    bf16x8 aA[4], aB[4];

#define TC(t) ((t) < 63 ? (t) : 63)   // clamp local tile index (uniform tail)

#define STAGE(slot, tl)                                                         \
    do {                                                                        \
        const unsigned short* src = Wbp + (size_t)(T0 + (tl)) * 131072;         \
        _Pragma("unroll")                                                       \
        for (int j = 0; j < 2; ++j) {                                           \
            __builtin_amdgcn_global_load_lds(                                   \
                (const __attribute__((address_space(1))) void*)(src + soff[j]), \
                (__attribute__((address_space(3))) void*)                      \
                    (Bs + (slot) * 4096 + dsto[j]),                             \
                16, 0, 0);                                                      \
        }                                                                       \
    } while (0)

#define LOADA(s, tl)                                                            \
    do {                                                                        \
        const unsigned short* Pt = Pcur + (size_t)(T0 + (tl)) * 32768;          \
        _Pragma("unroll")                                                       \
        for (int mi = 0; mi < 4; ++mi)                                          \
            s[mi] = *(const bf16x8*)(Pt + aoff[mi]);                            \
    } while (0)

#define COMPUTE(slot, s)                                                        \
    do {                                                                        \
        const unsigned short* Bb = Bs + (slot) * 4096;                          \
        bf16x8 bfr[4];                                                          \
        _Pragma("unroll")                                                       \
        for (int ni = 0; ni < 4; ++ni)                                          \
            bfr[ni] = *(const bf16x8*)(Bb + boff + ni * 512);                   \
        _Pragma("unroll")                                                       \
        for (int mi = 0; mi < 4; ++mi)                                          \
            _Pragma("unroll")                                                   \
            for (int ni = 0; ni < 4; ++ni)                                      \
                acc[mi][ni] = __builtin_amdgcn_mfma_f32_16x16x32_bf16(          \
                    s[mi], bfr[ni], acc[mi][ni], 0, 0, 0);                      \
    } while (0)

    // prologue: stages 0..2, A0 (issue order fixes vmcnt accounting)
    STAGE(0, 0);        // 2
    LOADA(aA, 0);       // 4
    STAGE(1, 1);        // 2
    STAGE(2, 2);        // 2
    // iter 0:
    LOADA(aB, 1);       // 4
    STAGE(3, 3);        // 2   -> 16 outstanding
    asm volatile("s_waitcnt vmcnt(10)" ::: "memory");  // S0 + A0 landed
    __builtin_amdgcn_s_barrier();
    COMPUTE(0, aA);

    // t = 1..62 in pairs; steady vmcnt(10)
    for (int tp = 0; tp < 31; ++tp) {
        const int t = 1 + 2 * tp;            // odd tile -> aB
        LOADA(aA, TC(t + 1));
        STAGE((t + 3) & 3, TC(t + 3));
        asm volatile("s_waitcnt vmcnt(10)" ::: "memory");
        __builtin_amdgcn_s_barrier();
        COMPUTE(t & 3, aB);

        const int u = t + 1;                 // even tile -> aA
        LOADA(aB, TC(u + 1));
        STAGE((u + 3) & 3, TC(u + 3));
        asm volatile("s_waitcnt vmcnt(10)" ::: "memory");
        __builtin_amdgcn_s_barrier();
        COMPUTE(u & 3, aA);
    }
    // t = 63 (odd -> aB)
    asm volatile("s_waitcnt vmcnt(0)" ::: "memory");
    __builtin_amdgcn_s_barrier();
    COMPUTE(3, aB);
#undef STAGE
#undef LOADA
#undef COMPUTE
#undef TC

    // partial write, bf16. C/D: col=lane&15, row=(lane>>4)*4+reg.
    const int lr = lane & 15, lk = lane >> 4;
    unsigned short* D = Dp + (size_t)ks * HALF_ELEMS;
#pragma unroll
    for (int mi = 0; mi < 4; ++mi) {
        int i0 = by * 128 + wm * 64 + mi * 16 + lk * 4;
#pragma unroll
        for (int ni = 0; ni < 4; ++ni) {
            int n = bx * 128 + wn * 64 + ni * 16 + lr;
#pragma unroll
            for (int r = 0; r < 4; ++r)
                D[(size_t)(i0 + r) * NODES + n] = f32_to_bf16(acc[mi][ni][r]);
        }
    }
}

// ---------------------------------------------------------------------------
// Kernel 4: combine 2 partials + epilogue, bf16 state. Thread = (b, 8 m's).
// Reads hb/xb (bf16), Dp (bf16); computes f32 in-register; writes hb + packed
// P (bf16). Last step: writes out (f32) only.
// ---------------------------------------------------------------------------
__global__ __launch_bounds__(256)
void combine_kernel(const unsigned short* __restrict__ Dp,
                    const unsigned short* __restrict__ xb,
                    unsigned short* __restrict__ hb,
                    unsigned short* __restrict__ Pnxt,
                    float* __restrict__ out) {
    int g  = blockIdx.x * 256 + threadIdx.x;   // 0..131071
    int b  = g >> 9;
    int mg = (g & 511) << 3;                   // m base (multiple of 8)
    size_t ebase = (size_t)b * DLEN + (size_t)mg * 4;   // element base (32 elems)

    u16x8 hw[4], xw[4];
#pragma unroll
    for (int j = 0; j < 4; ++j) {
        hw[j] = *(const u16x8*)(hb + ebase + j * 8);
        xw[j] = *(const u16x8*)(xb + ebase + j * 8);
    }
    u16x8 d0[4], d1[4];
#pragma unroll
    for (int c = 0; c < 4; ++c) {
        size_t off = (size_t)(b * 4 + c) * NODES + mg;
        d0[c] = *(const u16x8*)(Dp + off);
        d1[c] = *(const u16x8*)(Dp + HALF_ELEMS + off);
    }
    u16x8 pn[4];
    float o[8];
#pragma unroll
    for (int j = 0; j < 4; ++j) {           // word j = elems (m,c) [j*8 .. j*8+7]
        u16x8 hnw;
#pragma unroll
        for (int s = 0; s < 8; ++s) {
            int c = s & 3;
            int e = j * 2 + (s >> 2);        // m - mg
            float hv   = bf16_to_f32(hw[j][s]);
            float xv   = bf16_to_f32(xw[j][s]);
            float p    = bf16_to_f32(d0[c][e]) + bf16_to_f32(d1[c][e]);
            float rho  = tanhf(hv);
            float drive = p + xv;
            float hnew = 0.9f * hv + 0.1f * (1.0f - rho * rho) * drive;
            hnw[s] = f32_to_bf16(hnew);
            pn[c][e] = f32_to_bf16(tanhf(hnew));
            if (c == 0) o[e] = hnew;
        }
        hw[j] = hnw;
    }
    if (Pnxt) {   // not the last step: update hb and packed rho
#pragma unroll
        for (int j = 0; j < 4; ++j)
            *(u16x8*)(hb + ebase + j * 8) = hw[j];
#pragma unroll
        for (int c = 0; c < 4; ++c) {
            size_t pa = (size_t)(mg >> 5) * 32768 + (size_t)(b >> 2) * 512
                      + (size_t)(((b & 3) * 4 + c) | (((mg >> 3) & 3) << 4)) * 8;
            *(u16x8*)(Pnxt + pa) = pn[c];
        }
    }
    if (out) {
        *(f32x4*)(out + (size_t)b * NODES + mg)     = (f32x4){o[0], o[1], o[2], o[3]};
        *(f32x4*)(out + (size_t)b * NODES + mg + 4) = (f32x4){o[4], o[5], o[6], o[7]};
    }
}

// ---------------------------------------------------------------------------
extern "C" void kernel_launch(void* const* d_in, const int* in_sizes, int n_in,
                              void* d_out, int out_size, void* d_ws, size_t ws_size,
                              hipStream_t stream) {
    const float* x = (const float*)d_in[0];   // (256, 16384) f32
    const float* W = (const float*)d_in[1];   // (4096, 4096) f32
    float* out = (float*)d_out;               // (256, 4096) f32

    char* ws = (char*)d_ws;
    // ws: Wbp 32MB | P0 8MB | P1 8MB | hb 8MB | xb 8MB | Dp 16MB (= 80 MB)
    unsigned short* Wbp = (unsigned short*)(ws);
    unsigned short* P0  = (unsigned short*)(ws + ((size_t)32 << 20));
    unsigned short* P1  = (unsigned short*)(ws + ((size_t)40 << 20));
    unsigned short* hb  = (unsigned short*)(ws + ((size_t)48 << 20));
    unsigned short* xb  = (unsigned short*)(ws + ((size_t)56 << 20));
    unsigned short* Dp  = (unsigned short*)(ws + ((size_t)64 << 20));

    symw_kernel<<<dim3(64, 64), 256, 0, stream>>>(W, Wbp);
    init_kernel<<<dim3(4096), 256, 0, stream>>>(x, hb, xb, P0);

    unsigned short* pc = P0;
    unsigned short* pn = P1;
    for (int s = 0; s < 10; ++s) {
        gemm_kernel<<<dim3(512), 256, 0, stream>>>(pc, Wbp, Dp);
        combine_kernel<<<dim3(512), 256, 0, stream>>>(
            Dp, xb, hb, (s == 9) ? nullptr : pn, (s == 9) ? out : nullptr);
        unsigned short* t = pc; pc = pn; pn = t;
    }
}

// Round 15
// 538.147 us; speedup vs baseline: 1.2000x; 1.0230x over previous
//
#include <hip/hip_runtime.h>
#include <hip/hip_bf16.h>

// CliffordEPBottleneck: 10x { rho=tanh(h); drive=W_sym@rho+x; h=0.9h+0.1(1-rho^2)drive }
// Core: 10x GEMM (1024 x 4096 x 4096) bf16 MFMA.
//
// R15 = R14 with the gemm WAR race fixed. R14 staged into slot (t-1)%3
// BEFORE barrier(t) -> DMA could land while laggard waves' second ds_read
// round (new at BK=64) still read that slot (absmax 0.14). Fix (R12-validated
// order): vmcnt -> s_barrier -> STAGE(t+3, ring-4) -> LOADA -> COMPUTE.
// Stage target slot (t-1)&3 has all readers drained before barrier(t).
// Kept: BK=64 (32 K-steps, 32 MFMA/sync), fused symw, bf16 h/x state,
// frag-packed W/P, split-K=2, XCD-partitioned decode.

#define NODES 4096
#define KDIM  4096
#define MDIM  1024
#define DLEN  16384
#define HALF_ELEMS 4194304   // MDIM*NODES (one partial plane)

typedef __attribute__((ext_vector_type(8))) __bf16 bf16x8;
typedef __attribute__((ext_vector_type(8))) unsigned short u16x8;
typedef __attribute__((ext_vector_type(4))) unsigned short u16x4;
typedef __attribute__((ext_vector_type(4))) float  f32x4;

static __device__ __forceinline__ unsigned short f32_to_bf16(float f) {
    unsigned int u = __float_as_uint(f);
    u += 0x7fffu + ((u >> 16) & 1u);   // round-to-nearest-even
    return (unsigned short)(u >> 16);
}
static __device__ __forceinline__ float bf16_to_f32(unsigned short u) {
    return __uint_as_float(((unsigned int)u) << 16);
}

// packed W address for element (n, k):
static __device__ __forceinline__ size_t wbp_addr(int n, int k) {
    return ((size_t)(k >> 5) * 256 + (n >> 4)) * 512
         + (size_t)((n & 15) | (((k >> 3) & 3) << 4)) * 8 + (k & 7);
}

// ---------------------------------------------------------------------------
// Kernel 1: pair-fused symmetrize+pack. Block (tn, tm) with tm>=tn only.
// ---------------------------------------------------------------------------
__global__ __launch_bounds__(256)
void symw_kernel(const float* __restrict__ W, unsigned short* __restrict__ Wbp) {
    const int tn = blockIdx.y, tm = blockIdx.x;
    if (tm < tn) return;
    __shared__ float Ta[64][65];   // W[tn*64+r][tm*64+c]
    __shared__ float Tb[64][65];   // W[tm*64+r][tn*64+c]
    const int c  = threadIdx.x & 63;
    const int r0 = threadIdx.x >> 6;
#pragma unroll
    for (int rr = 0; rr < 16; ++rr) {
        int r = r0 * 16 + rr;
        Ta[r][c] = W[(size_t)(tn * 64 + r) * 4096 + tm * 64 + c];
        Tb[r][c] = W[(size_t)(tm * 64 + r) * 4096 + tn * 64 + c];
    }
    __syncthreads();
#pragma unroll
    for (int rr = 0; rr < 16; ++rr) {
        int r = r0 * 16 + rr;
        float v = 0.5f * (Ta[r][c] + Tb[c][r]);
        Wbp[wbp_addr(tn * 64 + r, tm * 64 + c)] = f32_to_bf16(v);
    }
    if (tm != tn) {
#pragma unroll
        for (int rr = 0; rr < 16; ++rr) {
            int r = r0 * 16 + rr;
            float v = 0.5f * (Tb[r][c] + Ta[c][r]);
            Wbp[wbp_addr(tm * 64 + r, tn * 64 + c)] = f32_to_bf16(v);
        }
    }
}

// ---------------------------------------------------------------------------
// Kernel 2: hb = bf16(x); xb = bf16(x); P0 = packed bf16(tanh(x)).
// ---------------------------------------------------------------------------
__global__ __launch_bounds__(256)
void init_kernel(const float* __restrict__ x,
                 unsigned short* __restrict__ hb,
                 unsigned short* __restrict__ xb,
                 unsigned short* __restrict__ P0) {
    int idx = blockIdx.x * blockDim.x + threadIdx.x;   // over B*NODES = 1M
    int b = idx >> 12;
    int m = idx & 4095;
    f32x4 xv = *(const f32x4*)(x + (size_t)idx * 4);
    u16x4 xq;
#pragma unroll
    for (int c = 0; c < 4; ++c) xq[c] = f32_to_bf16(xv[c]);
    *(u16x4*)(xb + (size_t)idx * 4) = xq;
    *(u16x4*)(hb + (size_t)idx * 4) = xq;
    size_t base = ((size_t)(m >> 5) * 64 + (b >> 2)) * 512
                + (size_t)((m >> 3) & 3) * 128 + (m & 7);
#pragma unroll
    for (int c = 0; c < 4; ++c) {
        P0[base + (size_t)((b & 3) * 4 + c) * 8] = f32_to_bf16(tanhf(xv[c]));
    }
}

// ---------------------------------------------------------------------------
// Kernel 3: split-K=2 GEMM, BK=64, ring-4, stage-after-barrier (race-free).
// grid 512 (flat, XCD-partitioned), 256 thr (4 waves 2x2), wave = 64x64.
// 32 K-steps; one barrier per K-step; 32 MFMA per wave per sync.
// ---------------------------------------------------------------------------
__global__ __launch_bounds__(256, 2)
void gemm_kernel(const unsigned short* __restrict__ Pcur,
                 const unsigned short* __restrict__ Wbp,
                 unsigned short* __restrict__ Dp) {
    __shared__ unsigned short Bs[4 * 8192];   // ring-4 x 16 KB (128n x 64k frag-major)

    // XCD-partitioned decode: xcd = id&7 owns bx in {4*xcd .. 4*xcd+3}
    const int id   = blockIdx.x;                       // 0..511
    const int bx   = (id & 7) * 4 + ((id >> 3) & 3);   // 0..31
    const int by   = (id >> 5) & 7;                    // 0..7
    const int ks   = id >> 8;                          // 0..1
    const int K32_0 = ks * 64;                         // first k32 frag index

    const int tid  = threadIdx.x;
    const int w    = tid >> 6;
    const int lane = tid & 63;
    const int wm   = w >> 1;                 // 0..1
    const int wn   = w & 1;                  // 0..1

    // staging: 4 chunks/thread (B tile = 16 KB = 1024 x 16B).
    // chunk c (0..1023): LDS frag f = c>>6 = kf*8+nf; source k32 = 2t+kf.
    size_t soff[4]; int dsto[4];
#pragma unroll
    for (int j = 0; j < 4; ++j) {
        int c  = tid + 256 * j;
        int f  = c >> 6;                     // 0..15
        int kf = f >> 3, nf = f & 7;
        soff[j] = (size_t)kf * 131072
                + ((size_t)(bx * 8 + nf)) * 512 + (size_t)(c & 63) * 8;
        dsto[j] = c * 8;
    }
    // A frags: rows (by*8 + wm*4 + mi) in 16-row units, + kk*32768 per k32
    size_t aoff[4];
#pragma unroll
    for (int mi = 0; mi < 4; ++mi)
        aoff[mi] = ((size_t)(by * 8 + wm * 4 + mi)) * 512 + (size_t)lane * 8;
    const int boff = (wn * 4) * 512 + lane * 8;   // + (kk*8+ni)*512 (+slot*8192)

    f32x4 acc[4][4];
#pragma unroll
    for (int mi = 0; mi < 4; ++mi)
#pragma unroll
        for (int ni = 0; ni < 4; ++ni)
            acc[mi][ni] = (f32x4){0.f, 0.f, 0.f, 0.f};

    bf16x8 aA[4][2], aB[4][2];

#define TC(t) ((t) < 31 ? (t) : 31)   // clamp local K-step (uniform tail)

#define STAGE(slot, tl)                                                         \
    do {                                                                        \
        const unsigned short* src = Wbp + (size_t)(K32_0 + 2 * (tl)) * 131072;  \
        _Pragma("unroll")                                                       \
        for (int j = 0; j < 4; ++j) {                                           \
            __builtin_amdgcn_global_load_lds(                                   \
                (const __attribute__((address_space(1))) void*)(src + soff[j]), \
                (__attribute__((address_space(3))) void*)                      \
                    (Bs + (slot) * 8192 + dsto[j]),                             \
                16, 0, 0);                                                      \
        }                                                                       \
    } while (0)

#define LOADA(s, tl)                                                            \
    do {                                                                        \
        const unsigned short* Pt = Pcur + (size_t)(K32_0 + 2 * (tl)) * 32768;   \
        _Pragma("unroll")                                                       \
        for (int mi = 0; mi < 4; ++mi)                                          \
            _Pragma("unroll")                                                   \
            for (int kk = 0; kk < 2; ++kk)                                      \
                s[mi][kk] = *(const bf16x8*)(Pt + (size_t)kk * 32768 + aoff[mi]); \
    } while (0)

#define COMPUTE(slot, s)                                                        \
    do {                                                                        \
        const unsigned short* Bb = Bs + (slot) * 8192;                          \
        _Pragma("unroll")                                                       \
        for (int kk = 0; kk < 2; ++kk) {                                        \
            bf16x8 bfr[4];                                                      \
            _Pragma("unroll")                                                   \
            for (int ni = 0; ni < 4; ++ni)                                      \
                bfr[ni] = *(const bf16x8*)(Bb + boff + (kk * 8 + ni) * 512);    \
            _Pragma("unroll")                                                   \
            for (int mi = 0; mi < 4; ++mi)                                      \
                _Pragma("unroll")                                               \
                for (int ni = 0; ni < 4; ++ni)                                  \
                    acc[mi][ni] = __builtin_amdgcn_mfma_f32_16x16x32_bf16(      \
                        s[mi][kk], bfr[ni], acc[mi][ni], 0, 0, 0);              \
        }                                                                       \
    } while (0)

    // prologue: stage tiles 0..2, load A(0). 20 VMEM ops outstanding.
    STAGE(0, 0);
    STAGE(1, 1);
    STAGE(2, 2);
    LOADA(aA, 0);

    // Steady iter t (safe order): vmcnt -> barrier -> STAGE(t+3 -> slot
    // (t-1)&3, readers drained pre-barrier) -> LOADA(t+1) -> COMPUTE(t).
    // Each wave's S(t) chunks are forced complete by its compiler A-wait at
    // COMPUTE(t-2), so barrier(t) => all waves' slot-t data landed.
    for (int tp = 0; tp < 16; ++tp) {
        const int t = 2 * tp;
        // even tile t -> aA
        if (t == 0) { asm volatile("s_waitcnt vmcnt(16)" ::: "memory"); }
        else        { asm volatile("s_waitcnt vmcnt(12)" ::: "memory"); }
        __builtin_amdgcn_s_barrier();
        STAGE((t + 3) & 3, TC(t + 3));
        LOADA(aB, TC(t + 1));
        COMPUTE(t & 3, aA);
        // odd tile t+1 -> aB
        asm volatile("s_waitcnt vmcnt(12)" ::: "memory");
        __builtin_amdgcn_s_barrier();
        STAGE((t + 4) & 3, TC(t + 4));
        LOADA(aA, TC(t + 2));
        COMPUTE((t + 1) & 3, aB);
    }
#undef STAGE
#undef LOADA
#undef COMPUTE
#undef TC

    // partial write, bf16. C/D: col=lane&15, row=(lane>>4)*4+reg.
    const int lr = lane & 15, lk = lane >> 4;
    unsigned short* D = Dp + (size_t)ks * HALF_ELEMS;
#pragma unroll
    for (int mi = 0; mi < 4; ++mi) {
        int i0 = by * 128 + wm * 64 + mi * 16 + lk * 4;
#pragma unroll
        for (int ni = 0; ni < 4; ++ni) {
            int n = bx * 128 + wn * 64 + ni * 16 + lr;
#pragma unroll
            for (int r = 0; r < 4; ++r)
                D[(size_t)(i0 + r) * NODES + n] = f32_to_bf16(acc[mi][ni][r]);
        }
    }
}

// ---------------------------------------------------------------------------
// Kernel 4: combine 2 partials + epilogue, bf16 state (R13 verbatim).
// ---------------------------------------------------------------------------
__global__ __launch_bounds__(256)
void combine_kernel(const unsigned short* __restrict__ Dp,
                    const unsigned short* __restrict__ xb,
                    unsigned short* __restrict__ hb,
                    unsigned short* __restrict__ Pnxt,
                    float* __restrict__ out) {
    int g  = blockIdx.x * 256 + threadIdx.x;   // 0..131071
    int b  = g >> 9;
    int mg = (g & 511) << 3;                   // m base (multiple of 8)
    size_t ebase = (size_t)b * DLEN + (size_t)mg * 4;   // element base (32 elems)

    u16x8 hw[4], xw[4];
#pragma unroll
    for (int j = 0; j < 4; ++j) {
        hw[j] = *(const u16x8*)(hb + ebase + j * 8);
        xw[j] = *(const u16x8*)(xb + ebase + j * 8);
    }
    u16x8 d0[4], d1[4];
#pragma unroll
    for (int c = 0; c < 4; ++c) {
        size_t off = (size_t)(b * 4 + c) * NODES + mg;
        d0[c] = *(const u16x8*)(Dp + off);
        d1[c] = *(const u16x8*)(Dp + HALF_ELEMS + off);
    }
    u16x8 pn[4];
    float o[8];
#pragma unroll
    for (int j = 0; j < 4; ++j) {           // word j = elems (m,c) [j*8 .. j*8+7]
        u16x8 hnw;
#pragma unroll
        for (int s = 0; s < 8; ++s) {
            int c = s & 3;
            int e = j * 2 + (s >> 2);        // m - mg
            float hv   = bf16_to_f32(hw[j][s]);
            float xv   = bf16_to_f32(xw[j][s]);
            float p    = bf16_to_f32(d0[c][e]) + bf16_to_f32(d1[c][e]);
            float rho  = tanhf(hv);
            float drive = p + xv;
            float hnew = 0.9f * hv + 0.1f * (1.0f - rho * rho) * drive;
            hnw[s] = f32_to_bf16(hnew);
            pn[c][e] = f32_to_bf16(tanhf(hnew));
            if (c == 0) o[e] = hnew;
        }
        hw[j] = hnw;
    }
    if (Pnxt) {   // not the last step: update hb and packed rho
#pragma unroll
        for (int j = 0; j < 4; ++j)
            *(u16x8*)(hb + ebase + j * 8) = hw[j];
#pragma unroll
        for (int c = 0; c < 4; ++c) {
            size_t pa = (size_t)(mg >> 5) * 32768 + (size_t)(b >> 2) * 512
                      + (size_t)(((b & 3) * 4 + c) | (((mg >> 3) & 3) << 4)) * 8;
            *(u16x8*)(Pnxt + pa) = pn[c];
        }
    }
    if (out) {
        *(f32x4*)(out + (size_t)b * NODES + mg)     = (f32x4){o[0], o[1], o[2], o[3]};
        *(f32x4*)(out + (size_t)b * NODES + mg + 4) = (f32x4){o[4], o[5], o[6], o[7]};
    }
}

// ---------------------------------------------------------------------------
extern "C" void kernel_launch(void* const* d_in, const int* in_sizes, int n_in,
                              void* d_out, int out_size, void* d_ws, size_t ws_size,
                              hipStream_t stream) {
    const float* x = (const float*)d_in[0];   // (256, 16384) f32
    const float* W = (const float*)d_in[1];   // (4096, 4096) f32
    float* out = (float*)d_out;               // (256, 4096) f32

    char* ws = (char*)d_ws;
    // ws: Wbp 32MB | P0 8MB | P1 8MB | hb 8MB | xb 8MB | Dp 16MB (= 80 MB)
    unsigned short* Wbp = (unsigned short*)(ws);
    unsigned short* P0  = (unsigned short*)(ws + ((size_t)32 << 20));
    unsigned short* P1  = (unsigned short*)(ws + ((size_t)40 << 20));
    unsigned short* hb  = (unsigned short*)(ws + ((size_t)48 << 20));
    unsigned short* xb  = (unsigned short*)(ws + ((size_t)56 << 20));
    unsigned short* Dp  = (unsigned short*)(ws + ((size_t)64 << 20));

    symw_kernel<<<dim3(64, 64), 256, 0, stream>>>(W, Wbp);
    init_kernel<<<dim3(4096), 256, 0, stream>>>(x, hb, xb, P0);

    unsigned short* pc = P0;
    unsigned short* pn = P1;
    for (int s = 0; s < 10; ++s) {
        gemm_kernel<<<dim3(512), 256, 0, stream>>>(pc, Wbp, Dp);
        combine_kernel<<<dim3(512), 256, 0, stream>>>(
            Dp, xb, hb, (s == 9) ? nullptr : pn, (s == 9) ? out : nullptr);
        unsigned short* t = pc; pc = pn; pn = t;
    }
}

// Round 16
// 535.613 us; speedup vs baseline: 1.2057x; 1.0047x over previous
//
#include <hip/hip_runtime.h>
#include <hip/hip_bf16.h>

// CliffordEPBottleneck: 10x { rho=tanh(h); drive=W_sym@rho+x; h=0.9h+0.1(1-rho^2)drive }
// Core: 10x GEMM (1024 x 4096 x 4096) bf16 MFMA.
//
// R16 = R15 with symw output coalesced. R15's symw (44 us, slowest dispatch)
// wrote Wbp as 16 scalar u16 stores/thread into the packed layout. Now each
// wave emits whole 1KB fragments: lane l computes its 8 MFMA-B-layout
// elements from LDS (Ta row-read + Tb col-read, 65-pad, 2-way banks = free)
// and stores one u16x8 at frag*1024 + lane*16 -> fully coalesced 1KB bursts.
// Pair-fusion kept (reads halved). gemm/combine/init frozen from R15.

#define NODES 4096
#define KDIM  4096
#define MDIM  1024
#define DLEN  16384
#define HALF_ELEMS 4194304   // MDIM*NODES (one partial plane)

typedef __attribute__((ext_vector_type(8))) __bf16 bf16x8;
typedef __attribute__((ext_vector_type(8))) unsigned short u16x8;
typedef __attribute__((ext_vector_type(4))) unsigned short u16x4;
typedef __attribute__((ext_vector_type(4))) float  f32x4;

static __device__ __forceinline__ unsigned short f32_to_bf16(float f) {
    unsigned int u = __float_as_uint(f);
    u += 0x7fffu + ((u >> 16) & 1u);   // round-to-nearest-even
    return (unsigned short)(u >> 16);
}
static __device__ __forceinline__ float bf16_to_f32(unsigned short u) {
    return __uint_as_float(((unsigned int)u) << 16);
}

// ---------------------------------------------------------------------------
// Kernel 1: pair-fused symmetrize+pack, frag-coalesced writes.
// Block (tn, tm), tm>=tn. Wave w emits frags f = 2w, 2w+1 of each output
// block; lane l owns packed bytes [l*16, l*16+16) of the frag.
// Frag (k32, n16) element for lane l, slot e: n16*16+(l&15) x k32*32+(l>>4)*8+e.
// ---------------------------------------------------------------------------
__global__ __launch_bounds__(256)
void symw_kernel(const float* __restrict__ W, unsigned short* __restrict__ Wbp) {
    const int tn = blockIdx.y, tm = blockIdx.x;
    if (tm < tn) return;
    __shared__ float Ta[64][65];   // W[tn*64+r][tm*64+c]
    __shared__ float Tb[64][65];   // W[tm*64+r][tn*64+c]
    const int c  = threadIdx.x & 63;
    const int r0 = threadIdx.x >> 6;
#pragma unroll
    for (int rr = 0; rr < 16; ++rr) {
        int r = r0 * 16 + rr;
        Ta[r][c] = W[(size_t)(tn * 64 + r) * 4096 + tm * 64 + c];
        Tb[r][c] = W[(size_t)(tm * 64 + r) * 4096 + tn * 64 + c];
    }
    __syncthreads();
    const int w    = threadIdx.x >> 6;   // 0..3
    const int lane = threadIdx.x & 63;
    const int lr   = lane & 15;
    const int le   = lane >> 4;          // 0..3
    // primary block: n in tn-block, k in tm-block
#pragma unroll
    for (int q = 0; q < 2; ++q) {
        int f   = w * 2 + q;             // 0..7
        int kf  = f >> 2;                // 0..1 (local k32)
        int nfl = f & 3;                 // 0..3 (local n16)
        int nl  = nfl * 16 + lr;
        int kl  = kf * 32 + le * 8;
        unsigned short v[8];
#pragma unroll
        for (int e = 0; e < 8; ++e)
            v[e] = f32_to_bf16(0.5f * (Ta[nl][kl + e] + Tb[kl + e][nl]));
        size_t frag = (size_t)(2 * tm + kf) * 256 + (4 * tn + nfl);
        *(u16x8*)(Wbp + frag * 512 + (size_t)lane * 8) = *(const u16x8*)v;
    }
    if (tm != tn) {
        // mirror block: n in tm-block, k in tn-block
#pragma unroll
        for (int q = 0; q < 2; ++q) {
            int f   = w * 2 + q;
            int kf  = f >> 2;
            int nfl = f & 3;
            int nl  = nfl * 16 + lr;
            int kl  = kf * 32 + le * 8;
            unsigned short v[8];
#pragma unroll
            for (int e = 0; e < 8; ++e)
                v[e] = f32_to_bf16(0.5f * (Tb[nl][kl + e] + Ta[kl + e][nl]));
            size_t frag = (size_t)(2 * tn + kf) * 256 + (4 * tm + nfl);
            *(u16x8*)(Wbp + frag * 512 + (size_t)lane * 8) = *(const u16x8*)v;
        }
    }
}

// ---------------------------------------------------------------------------
// Kernel 2: hb = bf16(x); xb = bf16(x); P0 = packed bf16(tanh(x)).
// ---------------------------------------------------------------------------
__global__ __launch_bounds__(256)
void init_kernel(const float* __restrict__ x,
                 unsigned short* __restrict__ hb,
                 unsigned short* __restrict__ xb,
                 unsigned short* __restrict__ P0) {
    int idx = blockIdx.x * blockDim.x + threadIdx.x;   // over B*NODES = 1M
    int b = idx >> 12;
    int m = idx & 4095;
    f32x4 xv = *(const f32x4*)(x + (size_t)idx * 4);
    u16x4 xq;
#pragma unroll
    for (int c = 0; c < 4; ++c) xq[c] = f32_to_bf16(xv[c]);
    *(u16x4*)(xb + (size_t)idx * 4) = xq;
    *(u16x4*)(hb + (size_t)idx * 4) = xq;
    size_t base = ((size_t)(m >> 5) * 64 + (b >> 2)) * 512
                + (size_t)((m >> 3) & 3) * 128 + (m & 7);
#pragma unroll
    for (int c = 0; c < 4; ++c) {
        P0[base + (size_t)((b & 3) * 4 + c) * 8] = f32_to_bf16(tanhf(xv[c]));
    }
}

// ---------------------------------------------------------------------------
// Kernel 3: split-K=2 GEMM, BK=64, ring-4, stage-after-barrier (R15 verbatim).
// grid 512 (flat, XCD-partitioned), 256 thr (4 waves 2x2), wave = 64x64.
// ---------------------------------------------------------------------------
__global__ __launch_bounds__(256, 2)
void gemm_kernel(const unsigned short* __restrict__ Pcur,
                 const unsigned short* __restrict__ Wbp,
                 unsigned short* __restrict__ Dp) {
    __shared__ unsigned short Bs[4 * 8192];   // ring-4 x 16 KB (128n x 64k frag-major)

    // XCD-partitioned decode: xcd = id&7 owns bx in {4*xcd .. 4*xcd+3}
    const int id   = blockIdx.x;                       // 0..511
    const int bx   = (id & 7) * 4 + ((id >> 3) & 3);   // 0..31
    const int by   = (id >> 5) & 7;                    // 0..7
    const int ks   = id >> 8;                          // 0..1
    const int K32_0 = ks * 64;                         // first k32 frag index

    const int tid  = threadIdx.x;
    const int w    = tid >> 6;
    const int lane = tid & 63;
    const int wm   = w >> 1;                 // 0..1
    const int wn   = w & 1;                  // 0..1

    // staging: 4 chunks/thread (B tile = 16 KB = 1024 x 16B).
    size_t soff[4]; int dsto[4];
#pragma unroll
    for (int j = 0; j < 4; ++j) {
        int c  = tid + 256 * j;
        int f  = c >> 6;                     // 0..15
        int kf = f >> 3, nf = f & 7;
        soff[j] = (size_t)kf * 131072
                + ((size_t)(bx * 8 + nf)) * 512 + (size_t)(c & 63) * 8;
        dsto[j] = c * 8;
    }
    // A frags: rows (by*8 + wm*4 + mi) in 16-row units, + kk*32768 per k32
    size_t aoff[4];
#pragma unroll
    for (int mi = 0; mi < 4; ++mi)
        aoff[mi] = ((size_t)(by * 8 + wm * 4 + mi)) * 512 + (size_t)lane * 8;
    const int boff = (wn * 4) * 512 + lane * 8;   // + (kk*8+ni)*512 (+slot*8192)

    f32x4 acc[4][4];
#pragma unroll
    for (int mi = 0; mi < 4; ++mi)
#pragma unroll
        for (int ni = 0; ni < 4; ++ni)
            acc[mi][ni] = (f32x4){0.f, 0.f, 0.f, 0.f};

    bf16x8 aA[4][2], aB[4][2];

#define TC(t) ((t) < 31 ? (t) : 31)   // clamp local K-step (uniform tail)

#define STAGE(slot, tl)                                                         \
    do {                                                                        \
        const unsigned short* src = Wbp + (size_t)(K32_0 + 2 * (tl)) * 131072;  \
        _Pragma("unroll")                                                       \
        for (int j = 0; j < 4; ++j) {                                           \
            __builtin_amdgcn_global_load_lds(                                   \
                (const __attribute__((address_space(1))) void*)(src + soff[j]), \
                (__attribute__((address_space(3))) void*)                      \
                    (Bs + (slot) * 8192 + dsto[j]),                             \
                16, 0, 0);                                                      \
        }                                                                       \
    } while (0)

#define LOADA(s, tl)                                                            \
    do {                                                                        \
        const unsigned short* Pt = Pcur + (size_t)(K32_0 + 2 * (tl)) * 32768;   \
        _Pragma("unroll")                                                       \
        for (int mi = 0; mi < 4; ++mi)                                          \
            _Pragma("unroll")                                                   \
            for (int kk = 0; kk < 2; ++kk)                                      \
                s[mi][kk] = *(const bf16x8*)(Pt + (size_t)kk * 32768 + aoff[mi]); \
    } while (0)

#define COMPUTE(slot, s)                                                        \
    do {                                                                        \
        const unsigned short* Bb = Bs + (slot) * 8192;                          \
        _Pragma("unroll")                                                       \
        for (int kk = 0; kk < 2; ++kk) {                                        \
            bf16x8 bfr[4];                                                      \
            _Pragma("unroll")                                                   \
            for (int ni = 0; ni < 4; ++ni)                                      \
                bfr[ni] = *(const bf16x8*)(Bb + boff + (kk * 8 + ni) * 512);    \
            _Pragma("unroll")                                                   \
            for (int mi = 0; mi < 4; ++mi)                                      \
                _Pragma("unroll")                                               \
                for (int ni = 0; ni < 4; ++ni)                                  \
                    acc[mi][ni] = __builtin_amdgcn_mfma_f32_16x16x32_bf16(      \
                        s[mi][kk], bfr[ni], acc[mi][ni], 0, 0, 0);              \
        }                                                                       \
    } while (0)

    // prologue: stage tiles 0..2, load A(0). 20 VMEM ops outstanding.
    STAGE(0, 0);
    STAGE(1, 1);
    STAGE(2, 2);
    LOADA(aA, 0);

    // Steady iter t (safe order): vmcnt -> barrier -> STAGE(t+3 -> slot
    // (t-1)&3, readers drained pre-barrier) -> LOADA(t+1) -> COMPUTE(t).
    for (int tp = 0; tp < 16; ++tp) {
        const int t = 2 * tp;
        // even tile t -> aA
        if (t == 0) { asm volatile("s_waitcnt vmcnt(16)" ::: "memory"); }
        else        { asm volatile("s_waitcnt vmcnt(12)" ::: "memory"); }
        __builtin_amdgcn_s_barrier();
        STAGE((t + 3) & 3, TC(t + 3));
        LOADA(aB, TC(t + 1));
        COMPUTE(t & 3, aA);
        // odd tile t+1 -> aB
        asm volatile("s_waitcnt vmcnt(12)" ::: "memory");
        __builtin_amdgcn_s_barrier();
        STAGE((t + 4) & 3, TC(t + 4));
        LOADA(aA, TC(t + 2));
        COMPUTE((t + 1) & 3, aB);
    }
#undef STAGE
#undef LOADA
#undef COMPUTE
#undef TC

    // partial write, bf16. C/D: col=lane&15, row=(lane>>4)*4+reg.
    const int lr = lane & 15, lk = lane >> 4;
    unsigned short* D = Dp + (size_t)ks * HALF_ELEMS;
#pragma unroll
    for (int mi = 0; mi < 4; ++mi) {
        int i0 = by * 128 + wm * 64 + mi * 16 + lk * 4;
#pragma unroll
        for (int ni = 0; ni < 4; ++ni) {
            int n = bx * 128 + wn * 64 + ni * 16 + lr;
#pragma unroll
            for (int r = 0; r < 4; ++r)
                D[(size_t)(i0 + r) * NODES + n] = f32_to_bf16(acc[mi][ni][r]);
        }
    }
}

// ---------------------------------------------------------------------------
// Kernel 4: combine 2 partials + epilogue, bf16 state (R13 verbatim).
// ---------------------------------------------------------------------------
__global__ __launch_bounds__(256)
void combine_kernel(const unsigned short* __restrict__ Dp,
                    const unsigned short* __restrict__ xb,
                    unsigned short* __restrict__ hb,
                    unsigned short* __restrict__ Pnxt,
                    float* __restrict__ out) {
    int g  = blockIdx.x * 256 + threadIdx.x;   // 0..131071
    int b  = g >> 9;
    int mg = (g & 511) << 3;                   // m base (multiple of 8)
    size_t ebase = (size_t)b * DLEN + (size_t)mg * 4;   // element base (32 elems)

    u16x8 hw[4], xw[4];
#pragma unroll
    for (int j = 0; j < 4; ++j) {
        hw[j] = *(const u16x8*)(hb + ebase + j * 8);
        xw[j] = *(const u16x8*)(xb + ebase + j * 8);
    }
    u16x8 d0[4], d1[4];
#pragma unroll
    for (int c = 0; c < 4; ++c) {
        size_t off = (size_t)(b * 4 + c) * NODES + mg;
        d0[c] = *(const u16x8*)(Dp + off);
        d1[c] = *(const u16x8*)(Dp + HALF_ELEMS + off);
    }
    u16x8 pn[4];
    float o[8];
#pragma unroll
    for (int j = 0; j < 4; ++j) {           // word j = elems (m,c) [j*8 .. j*8+7]
        u16x8 hnw;
#pragma unroll
        for (int s = 0; s < 8; ++s) {
            int c = s & 3;
            int e = j * 2 + (s >> 2);        // m - mg
            float hv   = bf16_to_f32(hw[j][s]);
            float xv   = bf16_to_f32(xw[j][s]);
            float p    = bf16_to_f32(d0[c][e]) + bf16_to_f32(d1[c][e]);
            float rho  = tanhf(hv);
            float drive = p + xv;
            float hnew = 0.9f * hv + 0.1f * (1.0f - rho * rho) * drive;
            hnw[s] = f32_to_bf16(hnew);
            pn[c][e] = f32_to_bf16(tanhf(hnew));
            if (c == 0) o[e] = hnew;
        }
        hw[j] = hnw;
    }
    if (Pnxt) {   // not the last step: update hb and packed rho
#pragma unroll
        for (int j = 0; j < 4; ++j)
            *(u16x8*)(hb + ebase + j * 8) = hw[j];
#pragma unroll
        for (int c = 0; c < 4; ++c) {
            size_t pa = (size_t)(mg >> 5) * 32768 + (size_t)(b >> 2) * 512
                      + (size_t)(((b & 3) * 4 + c) | (((mg >> 3) & 3) << 4)) * 8;
            *(u16x8*)(Pnxt + pa) = pn[c];
        }
    }
    if (out) {
        *(f32x4*)(out + (size_t)b * NODES + mg)     = (f32x4){o[0], o[1], o[2], o[3]};
        *(f32x4*)(out + (size_t)b * NODES + mg + 4) = (f32x4){o[4], o[5], o[6], o[7]};
    }
}

// ---------------------------------------------------------------------------
extern "C" void kernel_launch(void* const* d_in, const int* in_sizes, int n_in,
                              void* d_out, int out_size, void* d_ws, size_t ws_size,
                              hipStream_t stream) {
    const float* x = (const float*)d_in[0];   // (256, 16384) f32
    const float* W = (const float*)d_in[1];   // (4096, 4096) f32
    float* out = (float*)d_out;               // (256, 4096) f32

    char* ws = (char*)d_ws;
    // ws: Wbp 32MB | P0 8MB | P1 8MB | hb 8MB | xb 8MB | Dp 16MB (= 80 MB)
    unsigned short* Wbp = (unsigned short*)(ws);
    unsigned short* P0  = (unsigned short*)(ws + ((size_t)32 << 20));
    unsigned short* P1  = (unsigned short*)(ws + ((size_t)40 << 20));
    unsigned short* hb  = (unsigned short*)(ws + ((size_t)48 << 20));
    unsigned short* xb  = (unsigned short*)(ws + ((size_t)56 << 20));
    unsigned short* Dp  = (unsigned short*)(ws + ((size_t)64 << 20));

    symw_kernel<<<dim3(64, 64), 256, 0, stream>>>(W, Wbp);
    init_kernel<<<dim3(4096), 256, 0, stream>>>(x, hb, xb, P0);

    unsigned short* pc = P0;
    unsigned short* pn = P1;
    for (int s = 0; s < 10; ++s) {
        gemm_kernel<<<dim3(512), 256, 0, stream>>>(pc, Wbp, Dp);
        combine_kernel<<<dim3(512), 256, 0, stream>>>(
            Dp, xb, hb, (s == 9) ? nullptr : pn, (s == 9) ? out : nullptr);
        unsigned short* t = pc; pc = pn; pn = t;
    }
}